// Round 1
// baseline (570.990 us; speedup 1.0000x reference)
//
#include <hip/hip_runtime.h>

// B=4, S=2048, D=1024, H=16, Dh=64
// Outputs: [0, 8388608) = outs [B,S,D] fp32 ; [8388608, 16777216) = res2 [H,B,S,Dh] fp32

typedef __attribute__((ext_vector_type(8))) short bf16x8;
typedef __attribute__((ext_vector_type(4))) float f32x4;

#define MFMA16(a, b, c) __builtin_amdgcn_mfma_f32_16x16x32_bf16(a, b, c, 0, 0, 0)

__device__ __forceinline__ unsigned short fbf(float f) {
  union { float f; unsigned u; } x; x.f = f;
  unsigned r = x.u + 0x7fffu + ((x.u >> 16) & 1u);   // RNE
  return (unsigned short)(r >> 16);
}

// ---------------- fp32 -> bf16 convert (vectorized) ----------------
__global__ __launch_bounds__(256) void f2b_kernel(const float* __restrict__ s,
                                                  unsigned short* __restrict__ d, int n4) {
  int i = blockIdx.x * 256 + threadIdx.x;
  if (i >= n4) return;
  float4 v = ((const float4*)s)[i];
  ushort4 o;
  o.x = fbf(v.x); o.y = fbf(v.y); o.z = fbf(v.z); o.w = fbf(v.w);
  ((ushort4*)d)[i] = o;
}

// ---------------- mask int32 -> bitmask (64MB -> 2MB) ----------------
__global__ __launch_bounds__(256) void pack_mask_kernel(const int* __restrict__ m,
                                                        unsigned long long* __restrict__ o) {
  int i = blockIdx.x * 256 + threadIdx.x;   // grid covers exactly 16777216
  unsigned long long b = __ballot(m[i] != 0);
  if ((threadIdx.x & 63) == 0) o[i >> 6] = b;
}

// ---------------- bf16 GEMM: C[M,N] = A[M,K] * B[N,K]^T, M=8192, N=K=1024 ----------------
// EPI 0: store bf16 row-major [M,N]
// EPI 1: store bf16 permuted Vt[B=4,H=16,Dh=64,S=2048] (per-head transpose for PV B-operand)
// EPI 2: store fp32 + bias (final output)
template <int EPI>
__global__ __launch_bounds__(256) void gemm_bt(const unsigned short* __restrict__ A,
                                               const unsigned short* __restrict__ B,
                                               void* __restrict__ C,
                                               const float* __restrict__ bias) {
  __shared__ unsigned short Alds[128 * 32];
  __shared__ unsigned short Blds[128 * 32];
  const int tid = threadIdx.x;
  const int w = tid >> 6, l = tid & 63, q4 = l >> 4, c16 = l & 15;
  const int wm = w & 1, wn = w >> 1;
  const int mBase = blockIdx.y * 128, nBase = blockIdx.x * 128;

  f32x4 acc[4][4];
#pragma unroll
  for (int a0 = 0; a0 < 4; ++a0)
#pragma unroll
    for (int a1 = 0; a1 < 4; ++a1) acc[a0][a1] = (f32x4){0.f, 0.f, 0.f, 0.f};

  const int r0 = tid >> 2, cc0 = tid & 3;  // chunk j=0 rows 0..63 ; j=1 rows 64..127

  for (int kt = 0; kt < 32; ++kt) {
    __syncthreads();  // prior iteration's ds_reads done before overwrite
    const unsigned short* ga0 = A + (mBase + r0) * 1024 + kt * 32 + cc0 * 8;
    const unsigned short* ga1 = A + (mBase + 64 + r0) * 1024 + kt * 32 + cc0 * 8;
    const unsigned short* gb0 = B + (nBase + r0) * 1024 + kt * 32 + cc0 * 8;
    const unsigned short* gb1 = B + (nBase + 64 + r0) * 1024 + kt * 32 + cc0 * 8;
    __builtin_amdgcn_global_load_lds((const __attribute__((address_space(1))) void*)ga0,
                                     (__attribute__((address_space(3))) void*)(&Alds[tid * 8]),
                                     16, 0, 0);
    __builtin_amdgcn_global_load_lds((const __attribute__((address_space(1))) void*)ga1,
                                     (__attribute__((address_space(3))) void*)(&Alds[(tid + 256) * 8]),
                                     16, 0, 0);
    __builtin_amdgcn_global_load_lds((const __attribute__((address_space(1))) void*)gb0,
                                     (__attribute__((address_space(3))) void*)(&Blds[tid * 8]),
                                     16, 0, 0);
    __builtin_amdgcn_global_load_lds((const __attribute__((address_space(1))) void*)gb1,
                                     (__attribute__((address_space(3))) void*)(&Blds[(tid + 256) * 8]),
                                     16, 0, 0);
    __syncthreads();  // staging visible (compiler drains vmcnt before barrier)

    bf16x8 af[4], bfr[4];
#pragma unroll
    for (int mi = 0; mi < 4; ++mi)
      af[mi] = *(const bf16x8*)&Alds[(wm * 64 + mi * 16 + c16) * 32 + q4 * 8];
#pragma unroll
    for (int ni = 0; ni < 4; ++ni)
      bfr[ni] = *(const bf16x8*)&Blds[(wn * 64 + ni * 16 + c16) * 32 + q4 * 8];
#pragma unroll
    for (int mi = 0; mi < 4; ++mi)
#pragma unroll
      for (int ni = 0; ni < 4; ++ni) acc[mi][ni] = MFMA16(af[mi], bfr[ni], acc[mi][ni]);
  }

#pragma unroll
  for (int mi = 0; mi < 4; ++mi) {
#pragma unroll
    for (int ni = 0; ni < 4; ++ni) {
#pragma unroll
      for (int rg = 0; rg < 4; ++rg) {
        int row = mBase + wm * 64 + mi * 16 + q4 * 4 + rg;
        int col = nBase + wn * 64 + ni * 16 + c16;
        float v = acc[mi][ni][rg];
        if (EPI == 0) {
          ((unsigned short*)C)[row * 1024 + col] = fbf(v);
        } else if (EPI == 1) {
          int bb = row >> 11, rr = row & 2047;
          int hh = rr >> 7;
          int ss = ((rr & 127) << 4) | (col >> 6);
          int dh = col & 63;
          ((unsigned short*)C)[((bb * 16 + hh) * 64 + dh) * 2048 + ss] = fbf(v);
        } else {
          ((float*)C)[row * 1024 + col] = v + bias[col];
        }
      }
    }
  }
}

// ---------------- flash attention per (b, h, 128-row q tile) ----------------
// Qh/Kh: contiguous [2048,64] bf16 head views; Vth: [64,2048] bf16 (pre-transposed)
__global__ __launch_bounds__(256) void flash_kernel(const unsigned short* __restrict__ Q,
                                                    const unsigned short* __restrict__ K,
                                                    const unsigned short* __restrict__ Vt,
                                                    const uint4* __restrict__ mb,
                                                    unsigned short* __restrict__ Cws,
                                                    float* __restrict__ res2) {
  // padded strides: 72 and 136 bf16 so b128 frag reads spread over all 8 bank groups
  __shared__ unsigned short Klds[128 * 72];
  __shared__ unsigned short Vtlds[64 * 136];
  __shared__ unsigned short Plds[128 * 136];
  const int tid = threadIdx.x;
  const int w = tid >> 6, l = tid & 63, q4 = l >> 4, c16 = l & 15;
  const int qt = blockIdx.x, h = blockIdx.y, b = blockIdx.z;
  const unsigned short* Qh = Q + (b * 2048 + h * 128) * 1024;
  const unsigned short* Kh = K + (b * 2048 + h * 128) * 1024;
  const unsigned short* Vth = Vt + ((b * 16 + h) * 64) * 2048;

  // Q fragments live in registers for all 16 K-tiles
  bf16x8 qf[2][2];
#pragma unroll
  for (int i = 0; i < 2; ++i)
#pragma unroll
    for (int kc = 0; kc < 2; ++kc)
      qf[i][kc] = *(const bf16x8*)(Qh + (qt * 128 + w * 32 + i * 16 + c16) * 64 + kc * 32 + q4 * 8);

  f32x4 oacc[2][4];
#pragma unroll
  for (int i = 0; i < 2; ++i)
#pragma unroll
    for (int n = 0; n < 4; ++n) oacc[i][n] = (f32x4){0.f, 0.f, 0.f, 0.f};
  float lsum[2][4] = {{0.f, 0.f, 0.f, 0.f}, {0.f, 0.f, 0.f, 0.f}};

  const int krow = tid >> 1, khf = tid & 1;
  const int vrow = tid >> 2, vq = tid & 3;

  for (int kt = 0; kt < 16; ++kt) {
    {  // stage K tile [128][64] -> Klds[128][72]
      const unsigned short* g = Kh + (kt * 128 + krow) * 64 + khf * 32;
      unsigned short* d = Klds + krow * 72 + khf * 32;
#pragma unroll
      for (int c = 0; c < 4; ++c) *(bf16x8*)(d + c * 8) = *(const bf16x8*)(g + c * 8);
    }
    {  // stage Vt tile [64][128] -> Vtlds[64][136]
      const unsigned short* g = Vth + vrow * 2048 + kt * 128 + vq * 32;
      unsigned short* d = Vtlds + vrow * 136 + vq * 32;
#pragma unroll
      for (int c = 0; c < 4; ++c) *(bf16x8*)(d + c * 8) = *(const bf16x8*)(g + c * 8);
    }
    __syncthreads();

    // S = Q * K^T  (wave w owns q rows [w*32, w*32+32), all 128 k columns)
    f32x4 sacc[2][8];
#pragma unroll
    for (int i = 0; i < 2; ++i)
#pragma unroll
      for (int n = 0; n < 8; ++n) sacc[i][n] = (f32x4){0.f, 0.f, 0.f, 0.f};
#pragma unroll
    for (int kc = 0; kc < 2; ++kc) {
#pragma unroll
      for (int n = 0; n < 8; ++n) {
        bf16x8 kf = *(const bf16x8*)(Klds + (n * 16 + c16) * 72 + kc * 32 + q4 * 8);
        sacc[0][n] = MFMA16(qf[0][kc], kf, sacc[0][n]);
        sacc[1][n] = MFMA16(qf[1][kc], kf, sacc[1][n]);
      }
    }

    // mask + exp (no max-subtraction: faithful to reference), row-sum, P -> LDS (bf16)
#pragma unroll
    for (int i = 0; i < 2; ++i) {
#pragma unroll
      for (int rg = 0; rg < 4; ++rg) {
        int rloc = w * 32 + i * 16 + q4 * 4 + rg;
        int qglob = qt * 128 + rloc;
        uint4 m = mb[(b * 2048 + qglob) * 16 + kt];
        unsigned mw[4] = {m.x, m.y, m.z, m.w};
        float rs = 0.f;
#pragma unroll
        for (int n = 0; n < 8; ++n) {
          unsigned bit = (mw[n >> 1] >> ((n & 1) * 16 + c16)) & 1u;
          float pv = bit ? __expf(sacc[i][n][rg] * 0.125f) : 0.f;
          rs += pv;
          Plds[rloc * 136 + n * 16 + c16] = fbf(pv);
        }
#pragma unroll
        for (int d2 = 1; d2 < 16; d2 <<= 1) rs += __shfl_xor(rs, d2, 64);
        lsum[i][rg] += rs;  // all 16 lanes of the quad hold the row sum
      }
    }

    // O += P * V   (P rows are wave-private: no barrier needed, lgkmcnt orders same-wave LDS)
#pragma unroll
    for (int kc = 0; kc < 4; ++kc) {
      bf16x8 pf0 = *(const bf16x8*)(Plds + (w * 32 + c16) * 136 + kc * 32 + q4 * 8);
      bf16x8 pf1 = *(const bf16x8*)(Plds + (w * 32 + 16 + c16) * 136 + kc * 32 + q4 * 8);
#pragma unroll
      for (int n = 0; n < 4; ++n) {
        bf16x8 vf = *(const bf16x8*)(Vtlds + (n * 16 + c16) * 136 + kc * 32 + q4 * 8);
        oacc[0][n] = MFMA16(pf0, vf, oacc[0][n]);
        oacc[1][n] = MFMA16(pf1, vf, oacc[1][n]);
      }
    }
    __syncthreads();  // all LDS reads done before next staging
  }

  // epilogue: normalize (sum==0 -> 0 reproduces NaN->0), write res2 (fp32) + context (bf16)
#pragma unroll
  for (int i = 0; i < 2; ++i) {
#pragma unroll
    for (int rg = 0; rg < 4; ++rg) {
      float lv = lsum[i][rg];
      float rcp = (lv > 0.f) ? (1.0f / lv) : 0.f;
      int rloc = w * 32 + i * 16 + q4 * 4 + rg;
      int qglob = qt * 128 + rloc;
#pragma unroll
      for (int n = 0; n < 4; ++n) {
        int dh = n * 16 + c16;
        float ov = oacc[i][n][rg] * rcp;
        Cws[(b * 2048 + qglob) * 1024 + h * 64 + dh] = fbf(ov);
        res2[((h * 4 + b) * 2048 + qglob) * 64 + dh] = ov;
      }
    }
  }
}

extern "C" void kernel_launch(void* const* d_in, const int* in_sizes, int n_in,
                              void* d_out, int out_size, void* d_ws, size_t ws_size,
                              hipStream_t stream) {
  const float* query = (const float*)d_in[0];
  const float* key_t = (const float*)d_in[1];
  const float* value = (const float*)d_in[2];
  const int* mask = (const int*)d_in[3];
  const float* Wq = (const float*)d_in[4];
  const float* Wk = (const float*)d_in[5];
  const float* Wv = (const float*)d_in[6];
  const float* fcw = (const float*)d_in[7];
  const float* fcb = (const float*)d_in[8];
  float* out = (float*)d_out;

  char* ws = (char*)d_ws;
  unsigned short* qbf = (unsigned short*)(ws);                      // 16MB (later: Cws)
  unsigned short* kbf = (unsigned short*)(ws + (16u << 20));        // 16MB (later: mask bits)
  unsigned short* vbf = (unsigned short*)(ws + (32u << 20));        // 16MB
  unsigned short* wqb = (unsigned short*)(ws + (48u << 20));        // 2MB
  unsigned short* wkb = (unsigned short*)(ws + (50u << 20));
  unsigned short* wvb = (unsigned short*)(ws + (52u << 20));
  unsigned short* fwb = (unsigned short*)(ws + (54u << 20));
  unsigned short* Qf = (unsigned short*)(ws + (56u << 20));         // 16MB
  unsigned short* Kf = (unsigned short*)(ws + (72u << 20));         // 16MB
  unsigned short* Vt = (unsigned short*)(ws + (88u << 20));         // 16MB; total 104MB
  unsigned short* Cws = qbf;                                        // alias (qbf dead after Q-GEMM)
  unsigned long long* mbits = (unsigned long long*)kbf;             // alias (kbf dead after K-GEMM)

  // fp32 -> bf16
  f2b_kernel<<<8192, 256, 0, stream>>>(query, qbf, 2097152);
  f2b_kernel<<<8192, 256, 0, stream>>>(key_t, kbf, 2097152);
  f2b_kernel<<<8192, 256, 0, stream>>>(value, vbf, 2097152);
  f2b_kernel<<<1024, 256, 0, stream>>>(Wq, wqb, 262144);
  f2b_kernel<<<1024, 256, 0, stream>>>(Wk, wkb, 262144);
  f2b_kernel<<<1024, 256, 0, stream>>>(Wv, wvb, 262144);
  f2b_kernel<<<1024, 256, 0, stream>>>(fcw, fwb, 262144);

  // projections
  dim3 gg(8, 64);
  gemm_bt<0><<<gg, 256, 0, stream>>>(qbf, wqb, Qf, nullptr);
  gemm_bt<0><<<gg, 256, 0, stream>>>(kbf, wkb, Kf, nullptr);
  gemm_bt<1><<<gg, 256, 0, stream>>>(vbf, wvb, Vt, nullptr);

  pack_mask_kernel<<<65536, 256, 0, stream>>>(mask, mbits);

  flash_kernel<<<dim3(16, 16, 4), 256, 0, stream>>>(Qf, Kf, Vt, (const uint4*)mbits, Cws,
                                                    out + 8388608);

  gemm_bt<2><<<gg, 256, 0, stream>>>(Cws, fwb, out, fcb);
}

// Round 2
// 521.686 us; speedup vs baseline: 1.0945x; 1.0945x over previous
//
#include <hip/hip_runtime.h>

// B=4, S=2048, D=1024, H=16, Dh=64
// Outputs: [0, 8388608) = outs [B,S,D] fp32 ; [8388608, 16777216) = res2 [H,B,S,Dh] fp32

typedef __attribute__((ext_vector_type(8))) short bf16x8;
typedef __attribute__((ext_vector_type(4))) short bf16x4;
typedef __attribute__((ext_vector_type(4))) float f32x4;

#define MFMA32(a, b, c) __builtin_amdgcn_mfma_f32_16x16x32_bf16(a, b, c, 0, 0, 0)

#if __has_builtin(__builtin_amdgcn_mfma_f32_16x16x16bf16_1k)
#define MFMA_K16(a, b, c) __builtin_amdgcn_mfma_f32_16x16x16bf16_1k(a, b, c, 0, 0, 0)
#else
static __device__ __forceinline__ f32x4 mfma_k16_asm(bf16x4 a, bf16x4 b, f32x4 c) {
  f32x4 d;
  asm volatile("v_mfma_f32_16x16x16_bf16 %0, %1, %2, %3\n\ts_nop 7\n\ts_nop 7"
               : "=v"(d) : "v"(a), "v"(b), "v"(c));
  return d;
}
#define MFMA_K16(a, b, c) mfma_k16_asm(a, b, c)
#endif

static __device__ __forceinline__ float fast_exp2(float x) {
#if __has_builtin(__builtin_amdgcn_exp2f)
  return __builtin_amdgcn_exp2f(x);
#else
  return __expf(x * 0.69314718056f);
#endif
}

__device__ __forceinline__ unsigned short fbf(float f) {
  union { float f; unsigned u; } x; x.f = f;
  unsigned r = x.u + 0x7fffu + ((x.u >> 16) & 1u);   // RNE
  return (unsigned short)(r >> 16);
}

static __device__ __forceinline__ bf16x4 pack2(unsigned lo, unsigned hi) {
  union { unsigned u[2]; bf16x4 v; } x; x.u[0] = lo; x.u[1] = hi; return x.v;
}

// ---------------- fp32 -> bf16 convert (vectorized) ----------------
__global__ __launch_bounds__(256) void f2b_kernel(const float* __restrict__ s,
                                                  unsigned short* __restrict__ d, int n4) {
  int i = blockIdx.x * 256 + threadIdx.x;
  if (i >= n4) return;
  float4 v = ((const float4*)s)[i];
  ushort4 o;
  o.x = fbf(v.x); o.y = fbf(v.y); o.z = fbf(v.z); o.w = fbf(v.w);
  ((ushort4*)d)[i] = o;
}

// ---------------- mask int32 -> bitmask (64MB -> 2MB) ----------------
__global__ __launch_bounds__(256) void pack_mask_kernel(const int* __restrict__ m,
                                                        unsigned long long* __restrict__ o) {
  int i = blockIdx.x * 256 + threadIdx.x;   // grid covers exactly 16777216
  unsigned long long b = __ballot(m[i] != 0);
  if ((threadIdx.x & 63) == 0) o[i >> 6] = b;
}

// ---------------- bf16 GEMM: C[M,N] = A[M,K] * B[N,K]^T, M=8192, N=K=1024 ----------------
// EPI 0: store bf16 row-major [M,N], scaled
// EPI 1: store bf16 permuted Vt[B=4,H=16,Dh=64,S=2048] (per-head transpose for PV B-operand)
// EPI 2: store fp32 + bias (final output)
template <int EPI>
__global__ __launch_bounds__(256) void gemm_bt(const unsigned short* __restrict__ A,
                                               const unsigned short* __restrict__ B,
                                               void* __restrict__ C,
                                               const float* __restrict__ bias, float scale) {
  __shared__ unsigned short Alds[128 * 32];
  __shared__ unsigned short Blds[128 * 32];
  const int tid = threadIdx.x;
  const int w = tid >> 6, l = tid & 63, q4 = l >> 4, c16 = l & 15;
  const int wm = w & 1, wn = w >> 1;
  const int mBase = blockIdx.y * 128, nBase = blockIdx.x * 128;

  f32x4 acc[4][4];
#pragma unroll
  for (int a0 = 0; a0 < 4; ++a0)
#pragma unroll
    for (int a1 = 0; a1 < 4; ++a1) acc[a0][a1] = (f32x4){0.f, 0.f, 0.f, 0.f};

  const int r0 = tid >> 2, cc0 = tid & 3;

  for (int kt = 0; kt < 32; ++kt) {
    __syncthreads();
    const unsigned short* ga0 = A + (mBase + r0) * 1024 + kt * 32 + cc0 * 8;
    const unsigned short* ga1 = A + (mBase + 64 + r0) * 1024 + kt * 32 + cc0 * 8;
    const unsigned short* gb0 = B + (nBase + r0) * 1024 + kt * 32 + cc0 * 8;
    const unsigned short* gb1 = B + (nBase + 64 + r0) * 1024 + kt * 32 + cc0 * 8;
    __builtin_amdgcn_global_load_lds((const __attribute__((address_space(1))) void*)ga0,
                                     (__attribute__((address_space(3))) void*)(&Alds[tid * 8]),
                                     16, 0, 0);
    __builtin_amdgcn_global_load_lds((const __attribute__((address_space(1))) void*)ga1,
                                     (__attribute__((address_space(3))) void*)(&Alds[(tid + 256) * 8]),
                                     16, 0, 0);
    __builtin_amdgcn_global_load_lds((const __attribute__((address_space(1))) void*)gb0,
                                     (__attribute__((address_space(3))) void*)(&Blds[tid * 8]),
                                     16, 0, 0);
    __builtin_amdgcn_global_load_lds((const __attribute__((address_space(1))) void*)gb1,
                                     (__attribute__((address_space(3))) void*)(&Blds[(tid + 256) * 8]),
                                     16, 0, 0);
    __syncthreads();

    bf16x8 af[4], bfr[4];
#pragma unroll
    for (int mi = 0; mi < 4; ++mi)
      af[mi] = *(const bf16x8*)&Alds[(wm * 64 + mi * 16 + c16) * 32 + q4 * 8];
#pragma unroll
    for (int ni = 0; ni < 4; ++ni)
      bfr[ni] = *(const bf16x8*)&Blds[(wn * 64 + ni * 16 + c16) * 32 + q4 * 8];
#pragma unroll
    for (int mi = 0; mi < 4; ++mi)
#pragma unroll
      for (int ni = 0; ni < 4; ++ni) acc[mi][ni] = MFMA32(af[mi], bfr[ni], acc[mi][ni]);
  }

#pragma unroll
  for (int mi = 0; mi < 4; ++mi) {
#pragma unroll
    for (int ni = 0; ni < 4; ++ni) {
#pragma unroll
      for (int rg = 0; rg < 4; ++rg) {
        int row = mBase + wm * 64 + mi * 16 + q4 * 4 + rg;
        int col = nBase + wn * 64 + ni * 16 + c16;
        float v = acc[mi][ni][rg];
        if (EPI == 0) {
          ((unsigned short*)C)[row * 1024 + col] = fbf(v * scale);
        } else if (EPI == 1) {
          int bb = row >> 11, rr = row & 2047;
          int hh = rr >> 7;
          int ss = ((rr & 127) << 4) | (col >> 6);
          int dh = col & 63;
          ((unsigned short*)C)[((bb * 16 + hh) * 64 + dh) * 2048 + ss] = fbf(v);
        } else {
          ((float*)C)[row * 1024 + col] = v + bias[col];
        }
      }
    }
  }
}

// ---------------- flash attention per (b, h, 128-row q tile) ----------------
// Computes S^T = K·Q^T so P stays in registers (C-layout of S^T == A-layout of 16x16x16 PV).
// Row sums via an extra ones-column MFMA tile (Vtlds rows 64..79).
__global__ __launch_bounds__(256) void flash_kernel(const unsigned short* __restrict__ Q,
                                                    const unsigned short* __restrict__ K,
                                                    const unsigned short* __restrict__ Vt,
                                                    const uint4* __restrict__ mb,
                                                    unsigned short* __restrict__ Cws,
                                                    float* __restrict__ res2) {
  __shared__ unsigned short Klds[128 * 72];   // K tile [kcol][d], padded
  __shared__ unsigned short Vtlds[80 * 136];  // Vt tile [dh 0..63 | ones row 64][kcol], padded
  const int tid = threadIdx.x;
  const int w = tid >> 6, l = tid & 63, q4 = l >> 4, c16 = l & 15;
  const int qt = blockIdx.x, h = blockIdx.y, b = blockIdx.z;
  const unsigned short* Qh = Q + (b * 2048 + h * 128) * 1024;  // [2048][64] head view
  const unsigned short* Kh = K + (b * 2048 + h * 128) * 1024;
  const unsigned short* Vth = Vt + ((b * 16 + h) * 64) * 2048; // [64][2048]

  // ones/zeros rows 64..79 for the row-sum MFMA tile (written once)
  {
    int r = tid >> 4, c = (tid & 15) * 8;
    bf16x8 v;
    short fill = (r == 0) ? (short)0x3F80 : (short)0;  // row 64 = 1.0, rows 65..79 = 0
#pragma unroll
    for (int j = 0; j < 8; ++j) v[j] = fill;
    *(bf16x8*)(Vtlds + (64 + r) * 136 + c) = v;
  }

  // Q fragments (B-operand) live in registers for all 16 K-tiles
  bf16x8 qf[2][2];
#pragma unroll
  for (int i = 0; i < 2; ++i)
#pragma unroll
    for (int kc = 0; kc < 2; ++kc)
      qf[i][kc] = *(const bf16x8*)(Qh + (qt * 128 + w * 32 + i * 16 + c16) * 64 + kc * 32 + q4 * 8);

  f32x4 oacc[2][4], soacc[2];
#pragma unroll
  for (int i = 0; i < 2; ++i) {
    soacc[i] = (f32x4){0.f, 0.f, 0.f, 0.f};
#pragma unroll
    for (int t = 0; t < 4; ++t) oacc[i][t] = (f32x4){0.f, 0.f, 0.f, 0.f};
  }

  const int krow = tid >> 1, khf = tid & 1;
  const int vrow = tid >> 2, vq = tid & 3;
  const int q44 = q4 * 4;

  for (int kt = 0; kt < 16; ++kt) {
    {  // stage K tile [128][64] -> Klds[128][72]
      const unsigned short* g = Kh + (kt * 128 + krow) * 64 + khf * 32;
      unsigned short* d = Klds + krow * 72 + khf * 32;
#pragma unroll
      for (int c = 0; c < 4; ++c) *(bf16x8*)(d + c * 8) = *(const bf16x8*)(g + c * 8);
    }
    {  // stage Vt tile [64][128] -> Vtlds[64][136]
      const unsigned short* g = Vth + vrow * 2048 + kt * 128 + vq * 32;
      unsigned short* d = Vtlds + vrow * 136 + vq * 32;
#pragma unroll
      for (int c = 0; c < 4; ++c) *(bf16x8*)(d + c * 8) = *(const bf16x8*)(g + c * 8);
    }
    __syncthreads();

    // S^T = K·Q^T : lane holds S^T with q = base+c16, kcol = 16n + 4*q4 + rg
    f32x4 sacc[2][8];
#pragma unroll
    for (int i = 0; i < 2; ++i)
#pragma unroll
      for (int n = 0; n < 8; ++n) sacc[i][n] = (f32x4){0.f, 0.f, 0.f, 0.f};
#pragma unroll
    for (int kc = 0; kc < 2; ++kc) {
#pragma unroll
      for (int n = 0; n < 8; ++n) {
        bf16x8 kf = *(const bf16x8*)(Klds + (n * 16 + c16) * 72 + kc * 32 + q4 * 8);
        sacc[0][n] = MFMA32(kf, qf[0][kc], sacc[0][n]);
        sacc[1][n] = MFMA32(kf, qf[1][kc], sacc[1][n]);
      }
    }

    // exp2 (scale pre-folded into Q), pack to bf16 pairs, mask packed halves.
    bf16x4 pp[2][8][2];  // [i][kcol-chunk][reg-pair]
#pragma unroll
    for (int i = 0; i < 2; ++i) {
      int qglob = qt * 128 + w * 32 + i * 16 + c16;
      uint4 m = mb[(b * 2048 + qglob) * 16 + kt];
      unsigned mw[4] = {m.x, m.y, m.z, m.w};
#pragma unroll
      for (int n = 0; n < 8; ++n) {
        unsigned t = mw[n >> 1] >> ((n & 1) * 16 + q44);  // bits rg=0..3
        union { float f; unsigned u; } e0, e1, e2, e3;
        e0.f = fast_exp2(sacc[i][n][0]);
        e1.f = fast_exp2(sacc[i][n][1]);
        e2.f = fast_exp2(sacc[i][n][2]);
        e3.f = fast_exp2(sacc[i][n][3]);
        // round-half-up to bf16 and pack pairs (lo = lower kcol)
        unsigned p01 = __builtin_amdgcn_perm(e1.u + 0x8000u, e0.u + 0x8000u, 0x07060302u);
        unsigned p23 = __builtin_amdgcn_perm(e3.u + 0x8000u, e2.u + 0x8000u, 0x07060302u);
        // per-half masks from bits rg (0 or 0xFFFF per half)
        int m0 = __builtin_amdgcn_sbfe(t, 0, 1), m1 = __builtin_amdgcn_sbfe(t, 1, 1);
        int m2 = __builtin_amdgcn_sbfe(t, 2, 1), m3 = __builtin_amdgcn_sbfe(t, 3, 1);
        unsigned k01 = __builtin_amdgcn_perm((unsigned)m1, (unsigned)m0, 0x07060100u);
        unsigned k23 = __builtin_amdgcn_perm((unsigned)m3, (unsigned)m2, 0x07060100u);
        pp[i][n][0] = pack2(p01 & k01, p23 & k23);
        pp[i][n][1] = pp[i][n][0];  // placeholder removed below (kept for clarity of pair packing)
        pp[i][n][0] = pack2(p01 & k01, p23 & k23);
        pp[i][n][1] = pack2(p01 & k01, p23 & k23);
      }
    }
    // NOTE: pp[i][n][0] holds all 4 bf16 (two packed dwords); [1] unused duplicate is
    // eliminated by the compiler. A-frag for chunk n = pp[i][n][0].

    // O += P·V with 16x16x16 MFMA; B-frags (b64) shared across i. Tile t=4 = row sums.
#pragma unroll
    for (int n = 0; n < 8; ++n) {
#pragma unroll
      for (int t = 0; t < 5; ++t) {
        bf16x4 vfr = *(const bf16x4*)(Vtlds + (t * 16 + c16) * 136 + n * 16 + q44);
        if (t < 4) {
          oacc[0][t] = MFMA_K16(pp[0][n][0], vfr, oacc[0][t]);
          oacc[1][t] = MFMA_K16(pp[1][n][0], vfr, oacc[1][t]);
        } else {
          soacc[0] = MFMA_K16(pp[0][n][0], vfr, soacc[0]);
          soacc[1] = MFMA_K16(pp[1][n][0], vfr, soacc[1]);
        }
      }
    }
    __syncthreads();  // all LDS reads done before next staging
  }

  // epilogue: broadcast row sums from lanes c16==0, normalize, write res2 + context
#pragma unroll
  for (int i = 0; i < 2; ++i) {
    float srow[4];
#pragma unroll
    for (int rg = 0; rg < 4; ++rg) {
      float s = __shfl(soacc[i][rg], (l & 48), 64);
      srow[rg] = (s > 0.f) ? (1.0f / s) : 0.f;
    }
#pragma unroll
    for (int t = 0; t < 4; ++t) {
#pragma unroll
      for (int rg = 0; rg < 4; ++rg) {
        int q = qt * 128 + w * 32 + i * 16 + q4 * 4 + rg;
        int dh = t * 16 + c16;
        float ov = oacc[i][t][rg] * srow[rg];
        Cws[(b * 2048 + q) * 1024 + h * 64 + dh] = fbf(ov);
        res2[((h * 4 + b) * 2048 + q) * 64 + dh] = ov;
      }
    }
  }
}

extern "C" void kernel_launch(void* const* d_in, const int* in_sizes, int n_in,
                              void* d_out, int out_size, void* d_ws, size_t ws_size,
                              hipStream_t stream) {
  const float* query = (const float*)d_in[0];
  const float* key_t = (const float*)d_in[1];
  const float* value = (const float*)d_in[2];
  const int* mask = (const int*)d_in[3];
  const float* Wq = (const float*)d_in[4];
  const float* Wk = (const float*)d_in[5];
  const float* Wv = (const float*)d_in[6];
  const float* fcw = (const float*)d_in[7];
  const float* fcb = (const float*)d_in[8];
  float* out = (float*)d_out;

  char* ws = (char*)d_ws;
  unsigned short* qbf = (unsigned short*)(ws);                      // 16MB (later: Cws)
  unsigned short* kbf = (unsigned short*)(ws + (16u << 20));        // 16MB (later: mask bits)
  unsigned short* vbf = (unsigned short*)(ws + (32u << 20));        // 16MB
  unsigned short* wqb = (unsigned short*)(ws + (48u << 20));        // 2MB
  unsigned short* wkb = (unsigned short*)(ws + (50u << 20));
  unsigned short* wvb = (unsigned short*)(ws + (52u << 20));
  unsigned short* fwb = (unsigned short*)(ws + (54u << 20));
  unsigned short* Qf = (unsigned short*)(ws + (56u << 20));         // 16MB
  unsigned short* Kf = (unsigned short*)(ws + (72u << 20));         // 16MB
  unsigned short* Vt = (unsigned short*)(ws + (88u << 20));         // 16MB; total 104MB
  unsigned short* Cws = qbf;                                        // alias (qbf dead after Q-GEMM)
  unsigned long long* mbits = (unsigned long long*)kbf;             // alias (kbf dead after K-GEMM)

  // fp32 -> bf16
  f2b_kernel<<<8192, 256, 0, stream>>>(query, qbf, 2097152);
  f2b_kernel<<<8192, 256, 0, stream>>>(key_t, kbf, 2097152);
  f2b_kernel<<<8192, 256, 0, stream>>>(value, vbf, 2097152);
  f2b_kernel<<<1024, 256, 0, stream>>>(Wq, wqb, 262144);
  f2b_kernel<<<1024, 256, 0, stream>>>(Wk, wkb, 262144);
  f2b_kernel<<<1024, 256, 0, stream>>>(Wv, wvb, 262144);
  f2b_kernel<<<1024, 256, 0, stream>>>(fcw, fwb, 262144);

  // projections; Q pre-scaled by 1/8 * log2(e) so flash uses exp2 directly
  dim3 gg(8, 64);
  gemm_bt<0><<<gg, 256, 0, stream>>>(qbf, wqb, Qf, nullptr, 0.18033688f);
  gemm_bt<0><<<gg, 256, 0, stream>>>(kbf, wkb, Kf, nullptr, 1.0f);
  gemm_bt<1><<<gg, 256, 0, stream>>>(vbf, wvb, Vt, nullptr, 1.0f);

  pack_mask_kernel<<<65536, 256, 0, stream>>>(mask, mbits);

  flash_kernel<<<dim3(16, 16, 4), 256, 0, stream>>>(Qf, Kf, Vt, (const uint4*)mbits, Cws,
                                                    out + 8388608);

  gemm_bt<2><<<gg, 256, 0, stream>>>(Cws, fwb, out, fcb, 1.0f);
}

// Round 3
// 483.905 us; speedup vs baseline: 1.1800x; 1.0781x over previous
//
#include <hip/hip_runtime.h>

// B=4, S=2048, D=1024, H=16, Dh=64
// Outputs: [0, 8388608) = outs [B,S,D] fp32 ; [8388608, 16777216) = res2 [H,B,S,Dh] fp32

typedef __attribute__((ext_vector_type(8))) short bf16x8;
typedef __attribute__((ext_vector_type(4))) short bf16x4;
typedef __attribute__((ext_vector_type(4))) float f32x4;

#define MFMA32(a, b, c) __builtin_amdgcn_mfma_f32_16x16x32_bf16(a, b, c, 0, 0, 0)

#if __has_builtin(__builtin_amdgcn_mfma_f32_16x16x16bf16_1k)
#define MFMA_K16(a, b, c) __builtin_amdgcn_mfma_f32_16x16x16bf16_1k(a, b, c, 0, 0, 0)
#else
static __device__ __forceinline__ f32x4 mfma_k16_asm(bf16x4 a, bf16x4 b, f32x4 c) {
  f32x4 d;
  asm volatile("v_mfma_f32_16x16x16_bf16 %0, %1, %2, %3\n\ts_nop 7\n\ts_nop 7"
               : "=v"(d) : "v"(a), "v"(b), "v"(c));
  return d;
}
#define MFMA_K16(a, b, c) mfma_k16_asm(a, b, c)
#endif

static __device__ __forceinline__ float fast_exp2(float x) {
#if __has_builtin(__builtin_amdgcn_exp2f)
  return __builtin_amdgcn_exp2f(x);
#else
  return __expf(x * 0.69314718056f);
#endif
}

__device__ __forceinline__ unsigned short fbf(float f) {
  union { float f; unsigned u; } x; x.f = f;
  unsigned r = x.u + 0x7fffu + ((x.u >> 16) & 1u);   // RNE
  return (unsigned short)(r >> 16);
}

static __device__ __forceinline__ bf16x4 pack2(unsigned lo, unsigned hi) {
  union { unsigned u[2]; bf16x4 v; } x; x.u[0] = lo; x.u[1] = hi; return x.v;
}

// exp2 on 4 S-values, round to bf16, apply 4 mask bits (pre-shifted word), pack to bf16x4
static __device__ __forceinline__ bf16x4 epp(f32x4 s, unsigned pre, int sh) {
  union { float f; unsigned u; } e0, e1, e2, e3;
  e0.f = fast_exp2(s[0]); e1.f = fast_exp2(s[1]);
  e2.f = fast_exp2(s[2]); e3.f = fast_exp2(s[3]);
  unsigned p01 = __builtin_amdgcn_perm(e1.u + 0x8000u, e0.u + 0x8000u, 0x07060302u);
  unsigned p23 = __builtin_amdgcn_perm(e3.u + 0x8000u, e2.u + 0x8000u, 0x07060302u);
  int m0 = __builtin_amdgcn_sbfe(pre, sh + 0, 1), m1 = __builtin_amdgcn_sbfe(pre, sh + 1, 1);
  int m2 = __builtin_amdgcn_sbfe(pre, sh + 2, 1), m3 = __builtin_amdgcn_sbfe(pre, sh + 3, 1);
  unsigned k01 = __builtin_amdgcn_perm((unsigned)m1, (unsigned)m0, 0x07060100u);
  unsigned k23 = __builtin_amdgcn_perm((unsigned)m3, (unsigned)m2, 0x07060100u);
  return pack2(p01 & k01, p23 & k23);
}

// ---------------- fp32 -> bf16 converts (fused launches) ----------------
__global__ __launch_bounds__(256) void f2b3_kernel(const float* __restrict__ s0,
                                                   const float* __restrict__ s1,
                                                   const float* __restrict__ s2,
                                                   unsigned short* __restrict__ d0,
                                                   unsigned short* __restrict__ d1,
                                                   unsigned short* __restrict__ d2) {
  int z = blockIdx.y;
  const float* s = (z == 0) ? s0 : (z == 1) ? s1 : s2;
  unsigned short* d = (z == 0) ? d0 : (z == 1) ? d1 : d2;
  int i = blockIdx.x * 256 + threadIdx.x;
  float4 v = ((const float4*)s)[i];
  ushort4 o;
  o.x = fbf(v.x); o.y = fbf(v.y); o.z = fbf(v.z); o.w = fbf(v.w);
  ((ushort4*)d)[i] = o;
}

__global__ __launch_bounds__(256) void f2b4_kernel(const float* __restrict__ s0,
                                                   const float* __restrict__ s1,
                                                   const float* __restrict__ s2,
                                                   const float* __restrict__ s3,
                                                   unsigned short* __restrict__ d0,
                                                   unsigned short* __restrict__ d1,
                                                   unsigned short* __restrict__ d2,
                                                   unsigned short* __restrict__ d3) {
  int z = blockIdx.y;
  const float* s = (z == 0) ? s0 : (z == 1) ? s1 : (z == 2) ? s2 : s3;
  unsigned short* d = (z == 0) ? d0 : (z == 1) ? d1 : (z == 2) ? d2 : d3;
  int i = blockIdx.x * 256 + threadIdx.x;
  float4 v = ((const float4*)s)[i];
  ushort4 o;
  o.x = fbf(v.x); o.y = fbf(v.y); o.z = fbf(v.z); o.w = fbf(v.w);
  ((ushort4*)d)[i] = o;
}

// ---------------- mask int32 -> bitmask (64MB -> 2MB) ----------------
__global__ __launch_bounds__(256) void pack_mask_kernel(const int* __restrict__ m,
                                                        unsigned long long* __restrict__ o) {
  int i = blockIdx.x * 256 + threadIdx.x;
  unsigned long long b = __ballot(m[i] != 0);
  if ((threadIdx.x & 63) == 0) o[i >> 6] = b;
}

// ---------------- fused projections: C = A * W^T for z in {Q,K,V} ----------------
// z=0: Qf bf16 scaled by log2(e)/8 ; z=1: Kf bf16 ; z=2: Vt bf16 permuted [B,H,Dh,S]
__global__ __launch_bounds__(256) void proj_kernel(const unsigned short* __restrict__ A0,
                                                   const unsigned short* __restrict__ A1,
                                                   const unsigned short* __restrict__ A2,
                                                   const unsigned short* __restrict__ W0,
                                                   const unsigned short* __restrict__ W1,
                                                   const unsigned short* __restrict__ W2,
                                                   unsigned short* __restrict__ C0,
                                                   unsigned short* __restrict__ C1,
                                                   unsigned short* __restrict__ C2) {
  __shared__ unsigned short Alds[128 * 32];
  __shared__ unsigned short Blds[128 * 32];
  const int z = blockIdx.z;
  const unsigned short* A = (z == 0) ? A0 : (z == 1) ? A1 : A2;
  const unsigned short* B = (z == 0) ? W0 : (z == 1) ? W1 : W2;
  const int tid = threadIdx.x;
  const int w = tid >> 6, l = tid & 63, q4 = l >> 4, c16 = l & 15;
  const int wm = w & 1, wn = w >> 1;
  const int mBase = blockIdx.y * 128, nBase = blockIdx.x * 128;

  f32x4 acc[4][4];
#pragma unroll
  for (int a0 = 0; a0 < 4; ++a0)
#pragma unroll
    for (int a1 = 0; a1 < 4; ++a1) acc[a0][a1] = (f32x4){0.f, 0.f, 0.f, 0.f};

  const int r0 = tid >> 2, cc0 = tid & 3;

  for (int kt = 0; kt < 32; ++kt) {
    __syncthreads();
    const unsigned short* ga0 = A + (mBase + r0) * 1024 + kt * 32 + cc0 * 8;
    const unsigned short* ga1 = A + (mBase + 64 + r0) * 1024 + kt * 32 + cc0 * 8;
    const unsigned short* gb0 = B + (nBase + r0) * 1024 + kt * 32 + cc0 * 8;
    const unsigned short* gb1 = B + (nBase + 64 + r0) * 1024 + kt * 32 + cc0 * 8;
    __builtin_amdgcn_global_load_lds((const __attribute__((address_space(1))) void*)ga0,
                                     (__attribute__((address_space(3))) void*)(&Alds[tid * 8]),
                                     16, 0, 0);
    __builtin_amdgcn_global_load_lds((const __attribute__((address_space(1))) void*)ga1,
                                     (__attribute__((address_space(3))) void*)(&Alds[(tid + 256) * 8]),
                                     16, 0, 0);
    __builtin_amdgcn_global_load_lds((const __attribute__((address_space(1))) void*)gb0,
                                     (__attribute__((address_space(3))) void*)(&Blds[tid * 8]),
                                     16, 0, 0);
    __builtin_amdgcn_global_load_lds((const __attribute__((address_space(1))) void*)gb1,
                                     (__attribute__((address_space(3))) void*)(&Blds[(tid + 256) * 8]),
                                     16, 0, 0);
    __syncthreads();

    bf16x8 af[4], bfr[4];
#pragma unroll
    for (int mi = 0; mi < 4; ++mi)
      af[mi] = *(const bf16x8*)&Alds[(wm * 64 + mi * 16 + c16) * 32 + q4 * 8];
#pragma unroll
    for (int ni = 0; ni < 4; ++ni)
      bfr[ni] = *(const bf16x8*)&Blds[(wn * 64 + ni * 16 + c16) * 32 + q4 * 8];
#pragma unroll
    for (int mi = 0; mi < 4; ++mi)
#pragma unroll
      for (int ni = 0; ni < 4; ++ni) acc[mi][ni] = MFMA32(af[mi], bfr[ni], acc[mi][ni]);
  }

  const float scale = (z == 0) ? 0.18033688f : 1.0f;  // log2(e)/8 folded into Q
#pragma unroll
  for (int mi = 0; mi < 4; ++mi) {
#pragma unroll
    for (int ni = 0; ni < 4; ++ni) {
#pragma unroll
      for (int rg = 0; rg < 4; ++rg) {
        int row = mBase + wm * 64 + mi * 16 + q4 * 4 + rg;
        int col = nBase + wn * 64 + ni * 16 + c16;
        float v = acc[mi][ni][rg];
        if (z < 2) {
          unsigned short* C = (z == 0) ? C0 : C1;
          C[row * 1024 + col] = fbf(v * scale);
        } else {
          int bb = row >> 11, rr = row & 2047;
          int hh = rr >> 7;
          int ss = ((rr & 127) << 4) | (col >> 6);
          int dh = col & 63;
          C2[((bb * 16 + hh) * 64 + dh) * 2048 + ss] = fbf(v);
        }
      }
    }
  }
}

// ---------------- final GEMM: out = Cws * fc_w^T + bias (fp32 out) ----------------
__global__ __launch_bounds__(256) void gemm_out(const unsigned short* __restrict__ A,
                                                const unsigned short* __restrict__ B,
                                                float* __restrict__ C,
                                                const float* __restrict__ bias) {
  __shared__ unsigned short Alds[128 * 32];
  __shared__ unsigned short Blds[128 * 32];
  const int tid = threadIdx.x;
  const int w = tid >> 6, l = tid & 63, q4 = l >> 4, c16 = l & 15;
  const int wm = w & 1, wn = w >> 1;
  const int mBase = blockIdx.y * 128, nBase = blockIdx.x * 128;

  f32x4 acc[4][4];
#pragma unroll
  for (int a0 = 0; a0 < 4; ++a0)
#pragma unroll
    for (int a1 = 0; a1 < 4; ++a1) acc[a0][a1] = (f32x4){0.f, 0.f, 0.f, 0.f};

  const int r0 = tid >> 2, cc0 = tid & 3;

  for (int kt = 0; kt < 32; ++kt) {
    __syncthreads();
    const unsigned short* ga0 = A + (mBase + r0) * 1024 + kt * 32 + cc0 * 8;
    const unsigned short* ga1 = A + (mBase + 64 + r0) * 1024 + kt * 32 + cc0 * 8;
    const unsigned short* gb0 = B + (nBase + r0) * 1024 + kt * 32 + cc0 * 8;
    const unsigned short* gb1 = B + (nBase + 64 + r0) * 1024 + kt * 32 + cc0 * 8;
    __builtin_amdgcn_global_load_lds((const __attribute__((address_space(1))) void*)ga0,
                                     (__attribute__((address_space(3))) void*)(&Alds[tid * 8]),
                                     16, 0, 0);
    __builtin_amdgcn_global_load_lds((const __attribute__((address_space(1))) void*)ga1,
                                     (__attribute__((address_space(3))) void*)(&Alds[(tid + 256) * 8]),
                                     16, 0, 0);
    __builtin_amdgcn_global_load_lds((const __attribute__((address_space(1))) void*)gb0,
                                     (__attribute__((address_space(3))) void*)(&Blds[tid * 8]),
                                     16, 0, 0);
    __builtin_amdgcn_global_load_lds((const __attribute__((address_space(1))) void*)gb1,
                                     (__attribute__((address_space(3))) void*)(&Blds[(tid + 256) * 8]),
                                     16, 0, 0);
    __syncthreads();

    bf16x8 af[4], bfr[4];
#pragma unroll
    for (int mi = 0; mi < 4; ++mi)
      af[mi] = *(const bf16x8*)&Alds[(wm * 64 + mi * 16 + c16) * 32 + q4 * 8];
#pragma unroll
    for (int ni = 0; ni < 4; ++ni)
      bfr[ni] = *(const bf16x8*)&Blds[(wn * 64 + ni * 16 + c16) * 32 + q4 * 8];
#pragma unroll
    for (int mi = 0; mi < 4; ++mi)
#pragma unroll
      for (int ni = 0; ni < 4; ++ni) acc[mi][ni] = MFMA32(af[mi], bfr[ni], acc[mi][ni]);
  }

#pragma unroll
  for (int mi = 0; mi < 4; ++mi) {
#pragma unroll
    for (int ni = 0; ni < 4; ++ni) {
#pragma unroll
      for (int rg = 0; rg < 4; ++rg) {
        int row = mBase + wm * 64 + mi * 16 + q4 * 4 + rg;
        int col = nBase + wn * 64 + ni * 16 + c16;
        C[row * 1024 + col] = acc[mi][ni][rg] + bias[col];
      }
    }
  }
}

// ---------------- flash attention per (b, h, 128-row q tile) ----------------
// S^T = K·Q^T (P stays in registers), O^T = Vt·P^T (vectorized epilogue),
// row sums via constant ones A-frag MFMA (every lane of column q holds the sum).
// K/Vt staged via global_load_lds with XOR-16B swizzle => conflict-free LDS reads.
__global__ __launch_bounds__(256) void flash_kernel(const unsigned short* __restrict__ Q,
                                                    const unsigned short* __restrict__ K,
                                                    const unsigned short* __restrict__ Vt,
                                                    const uint4* __restrict__ mb,
                                                    unsigned short* __restrict__ Cws,
                                                    float* __restrict__ res2) {
  __shared__ unsigned short Klds[128 * 64];   // [kcol][granule^ (kcol&7)]
  __shared__ unsigned short Vtlds[64 * 128];  // [dh][granule ^ (dh&15)]
  const int tid = threadIdx.x;
  const int w = tid >> 6, l = tid & 63, q4 = l >> 4, c16 = l & 15;
  const int q44 = q4 * 4;
  const int qt = blockIdx.x, h = blockIdx.y, b = blockIdx.z;
  const unsigned short* Qh = Q + (b * 2048 + h * 128) * 1024;
  const unsigned short* Kh = K + (b * 2048 + h * 128) * 1024;
  const unsigned short* Vth = Vt + (b * 16 + h) * 64 * 2048;

  // Q B-frags in registers for all 16 K-tiles
  bf16x8 qf[2][2];
#pragma unroll
  for (int i = 0; i < 2; ++i)
#pragma unroll
    for (int kc = 0; kc < 2; ++kc)
      qf[i][kc] = *(const bf16x8*)(Qh + (qt * 128 + w * 32 + i * 16 + c16) * 64 + kc * 32 + q4 * 8);

  const uint4* mrow0 = mb + (b * 2048 + qt * 128 + w * 32 + c16) * 16;
  const uint4* mrow1 = mrow0 + 16 * 16;  // +16 q rows

  // staging lane offsets (global side carries the swizzle; LDS side is lane-linear)
  const int kOff = (tid >> 3) * 64 + (((tid & 7) ^ ((tid >> 3) & 7)) * 8);
  const int vOff = (tid >> 4) * 2048 + (((tid & 15) ^ (tid >> 4)) * 8);

  // QK read lane bases (shorts): row=16n+c16, granule (kc*4+q4)^(c16&7)
  const int kb0 = c16 * 64 + ((q4 ^ (c16 & 7)) * 8);
  const int kb1 = kb0 ^ 32;
  // PV read pieces: row=16t+c16, granule (2n+(q4>>1))^c16, 8B half q4&1
  const int vbase = c16 * 128 + (q4 & 1) * 4;
  const int c16e = c16 & 14;
  const int lowb = (q4 >> 1) ^ (c16 & 1);

  const bf16x4 kOnes = {(short)0x3F80, (short)0x3F80, (short)0x3F80, (short)0x3F80};

  f32x4 oacc[2][4], soacc[2];
#pragma unroll
  for (int i = 0; i < 2; ++i) {
    soacc[i] = (f32x4){0.f, 0.f, 0.f, 0.f};
#pragma unroll
    for (int t = 0; t < 4; ++t) oacc[i][t] = (f32x4){0.f, 0.f, 0.f, 0.f};
  }

  for (int kt = 0; kt < 16; ++kt) {
    const unsigned short* gk = Kh + kt * 8192 + kOff;
    const unsigned short* gv = Vth + kt * 128 + vOff;
#pragma unroll
    for (int j = 0; j < 4; ++j) {
      __builtin_amdgcn_global_load_lds((const __attribute__((address_space(1))) void*)(gk + j * 2048),
                                       (__attribute__((address_space(3))) void*)(&Klds[(j * 256 + tid) * 8]),
                                       16, 0, 0);
      __builtin_amdgcn_global_load_lds((const __attribute__((address_space(1))) void*)(gv + j * 32768),
                                       (__attribute__((address_space(3))) void*)(&Vtlds[(j * 256 + tid) * 8]),
                                       16, 0, 0);
    }
    // mask rows (overlaps the DMA)
    uint4 m0 = mrow0[kt], m1 = mrow1[kt];
    unsigned pre0[4] = {m0.x >> q44, m0.y >> q44, m0.z >> q44, m0.w >> q44};
    unsigned pre1[4] = {m1.x >> q44, m1.y >> q44, m1.z >> q44, m1.w >> q44};
    __syncthreads();

#pragma unroll
    for (int n = 0; n < 8; ++n) {
      bf16x8 kf0 = *(const bf16x8*)(Klds + kb0 + n * 1024);
      bf16x8 kf1 = *(const bf16x8*)(Klds + kb1 + n * 1024);
      f32x4 s0 = (f32x4){0.f, 0.f, 0.f, 0.f}, s1 = (f32x4){0.f, 0.f, 0.f, 0.f};
      s0 = MFMA32(kf0, qf[0][0], s0);
      s0 = MFMA32(kf1, qf[0][1], s0);
      s1 = MFMA32(kf0, qf[1][0], s1);
      s1 = MFMA32(kf1, qf[1][1], s1);

      int sh = (n & 1) * 16;
      bf16x4 pp0 = epp(s0, pre0[n >> 1], sh);
      bf16x4 pp1 = epp(s1, pre1[n >> 1], sh);

      int gsn = ((2 * n) ^ c16e) | lowb;
      int va = vbase + gsn * 8;
#pragma unroll
      for (int t = 0; t < 4; ++t) {
        bf16x4 vf = *(const bf16x4*)(Vtlds + va + t * 2048);
        oacc[0][t] = MFMA_K16(vf, pp0, oacc[0][t]);
        oacc[1][t] = MFMA_K16(vf, pp1, oacc[1][t]);
      }
      soacc[0] = MFMA_K16(kOnes, pp0, soacc[0]);
      soacc[1] = MFMA_K16(kOnes, pp1, soacc[1]);
    }
    __syncthreads();
  }

  // epilogue: lane (c16,q4) holds O[q=base+i*16+c16][dh=16t+q44+rg]; soacc = rowsum(q)
#pragma unroll
  for (int i = 0; i < 2; ++i) {
    float sum = soacc[i][0];
    float rcp = (sum > 0.f) ? (1.0f / sum) : 0.f;  // sum==0 -> 0 reproduces NaN->0
    int q = qt * 128 + w * 32 + i * 16 + c16;
    float* rp = res2 + (((h * 4 + b) * 2048 + q) * 64 + q44);
    unsigned short* cp = Cws + ((b * 2048 + q) * 1024 + h * 64 + q44);
#pragma unroll
    for (int t = 0; t < 4; ++t) {
      float o0 = oacc[i][t][0] * rcp, o1 = oacc[i][t][1] * rcp;
      float o2 = oacc[i][t][2] * rcp, o3 = oacc[i][t][3] * rcp;
      float4 fo = {o0, o1, o2, o3};
      *(float4*)(rp + t * 16) = fo;
      ushort4 cv = {fbf(o0), fbf(o1), fbf(o2), fbf(o3)};
      *(ushort4*)(cp + t * 16) = cv;
    }
  }
}

extern "C" void kernel_launch(void* const* d_in, const int* in_sizes, int n_in,
                              void* d_out, int out_size, void* d_ws, size_t ws_size,
                              hipStream_t stream) {
  const float* query = (const float*)d_in[0];
  const float* key_t = (const float*)d_in[1];
  const float* value = (const float*)d_in[2];
  const int* mask = (const int*)d_in[3];
  const float* Wq = (const float*)d_in[4];
  const float* Wk = (const float*)d_in[5];
  const float* Wv = (const float*)d_in[6];
  const float* fcw = (const float*)d_in[7];
  const float* fcb = (const float*)d_in[8];
  float* out = (float*)d_out;

  char* ws = (char*)d_ws;
  unsigned short* qbf = (unsigned short*)(ws);                      // 16MB (later: Cws)
  unsigned short* kbf = (unsigned short*)(ws + (16u << 20));        // 16MB (later: mask bits)
  unsigned short* vbf = (unsigned short*)(ws + (32u << 20));        // 16MB
  unsigned short* wqb = (unsigned short*)(ws + (48u << 20));        // 2MB
  unsigned short* wkb = (unsigned short*)(ws + (50u << 20));
  unsigned short* wvb = (unsigned short*)(ws + (52u << 20));
  unsigned short* fwb = (unsigned short*)(ws + (54u << 20));
  unsigned short* Qf = (unsigned short*)(ws + (56u << 20));         // 16MB
  unsigned short* Kf = (unsigned short*)(ws + (72u << 20));         // 16MB
  unsigned short* Vt = (unsigned short*)(ws + (88u << 20));         // 16MB; total 104MB
  unsigned short* Cws = qbf;                                        // alias (qbf dead after proj)
  unsigned long long* mbits = (unsigned long long*)kbf;             // alias (kbf dead after proj)

  f2b3_kernel<<<dim3(8192, 3), 256, 0, stream>>>(query, key_t, value, qbf, kbf, vbf);
  f2b4_kernel<<<dim3(1024, 4), 256, 0, stream>>>(Wq, Wk, Wv, fcw, wqb, wkb, wvb, fwb);

  proj_kernel<<<dim3(8, 64, 3), 256, 0, stream>>>(qbf, kbf, vbf, wqb, wkb, wvb, Qf, Kf, Vt);

  pack_mask_kernel<<<65536, 256, 0, stream>>>(mask, mbits);

  flash_kernel<<<dim3(16, 16, 4), 256, 0, stream>>>(Qf, Kf, Vt, (const uint4*)mbits, Cws,
                                                    out + 8388608);

  gemm_out<<<dim3(8, 64), 256, 0, stream>>>(Cws, fwb, out, fcb);
}

// Round 4
// 460.578 us; speedup vs baseline: 1.2397x; 1.0506x over previous
//
#include <hip/hip_runtime.h>

// B=4, S=2048, D=1024, H=16, Dh=64
// Outputs: [0, 8388608) = outs [B,S,D] fp32 ; [8388608, 16777216) = res2 [H,B,S,Dh] fp32

typedef __attribute__((ext_vector_type(8))) short bf16x8;
typedef __attribute__((ext_vector_type(4))) short bf16x4;
typedef __attribute__((ext_vector_type(4))) float f32x4;

#define MFMA32(a, b, c) __builtin_amdgcn_mfma_f32_16x16x32_bf16(a, b, c, 0, 0, 0)

static __device__ __forceinline__ float fast_exp2(float x) {
#if __has_builtin(__builtin_amdgcn_exp2f)
  return __builtin_amdgcn_exp2f(x);
#else
  return __expf(x * 0.69314718056f);
#endif
}

__device__ __forceinline__ unsigned short fbf(float f) {
  union { float f; unsigned u; } x; x.f = f;
  unsigned r = x.u + 0x7fffu + ((x.u >> 16) & 1u);   // RNE
  return (unsigned short)(r >> 16);
}

static __device__ __forceinline__ bf16x4 pack2(unsigned lo, unsigned hi) {
  union { unsigned u[2]; bf16x4 v; } x; x.u[0] = lo; x.u[1] = hi; return x.v;
}

static __device__ __forceinline__ bf16x8 cat2(bf16x4 lo, bf16x4 hi) {
  union { bf16x4 h[2]; bf16x8 v; } x; x.h[0] = lo; x.h[1] = hi; return x.v;
}

// exp2 on 4 S-values, round to bf16, apply 4 mask bits (pre-shifted word), pack to bf16x4
static __device__ __forceinline__ bf16x4 epp(f32x4 s, unsigned pre, int sh) {
  union { float f; unsigned u; } e0, e1, e2, e3;
  e0.f = fast_exp2(s[0]); e1.f = fast_exp2(s[1]);
  e2.f = fast_exp2(s[2]); e3.f = fast_exp2(s[3]);
  unsigned p01 = __builtin_amdgcn_perm(e1.u + 0x8000u, e0.u + 0x8000u, 0x07060302u);
  unsigned p23 = __builtin_amdgcn_perm(e3.u + 0x8000u, e2.u + 0x8000u, 0x07060302u);
  int m0 = __builtin_amdgcn_sbfe(pre, sh + 0, 1), m1 = __builtin_amdgcn_sbfe(pre, sh + 1, 1);
  int m2 = __builtin_amdgcn_sbfe(pre, sh + 2, 1), m3 = __builtin_amdgcn_sbfe(pre, sh + 3, 1);
  unsigned k01 = __builtin_amdgcn_perm((unsigned)m1, (unsigned)m0, 0x07060100u);
  unsigned k23 = __builtin_amdgcn_perm((unsigned)m3, (unsigned)m2, 0x07060100u);
  return pack2(p01 & k01, p23 & k23);
}

// ---------------- fp32 -> bf16 converts (fused launches) ----------------
__global__ __launch_bounds__(256) void f2b3_kernel(const float* __restrict__ s0,
                                                   const float* __restrict__ s1,
                                                   const float* __restrict__ s2,
                                                   unsigned short* __restrict__ d0,
                                                   unsigned short* __restrict__ d1,
                                                   unsigned short* __restrict__ d2) {
  int z = blockIdx.y;
  const float* s = (z == 0) ? s0 : (z == 1) ? s1 : s2;
  unsigned short* d = (z == 0) ? d0 : (z == 1) ? d1 : d2;
  int i = blockIdx.x * 256 + threadIdx.x;
  float4 v = ((const float4*)s)[i];
  ushort4 o;
  o.x = fbf(v.x); o.y = fbf(v.y); o.z = fbf(v.z); o.w = fbf(v.w);
  ((ushort4*)d)[i] = o;
}

__global__ __launch_bounds__(256) void f2b4_kernel(const float* __restrict__ s0,
                                                   const float* __restrict__ s1,
                                                   const float* __restrict__ s2,
                                                   const float* __restrict__ s3,
                                                   unsigned short* __restrict__ d0,
                                                   unsigned short* __restrict__ d1,
                                                   unsigned short* __restrict__ d2,
                                                   unsigned short* __restrict__ d3) {
  int z = blockIdx.y;
  const float* s = (z == 0) ? s0 : (z == 1) ? s1 : (z == 2) ? s2 : s3;
  unsigned short* d = (z == 0) ? d0 : (z == 1) ? d1 : (z == 2) ? d2 : d3;
  int i = blockIdx.x * 256 + threadIdx.x;
  float4 v = ((const float4*)s)[i];
  ushort4 o;
  o.x = fbf(v.x); o.y = fbf(v.y); o.z = fbf(v.z); o.w = fbf(v.w);
  ((ushort4*)d)[i] = o;
}

// ---------------- mask int32 -> bitmask, kt-major: o[(kt*8192+row)*2 + h] ----------------
__global__ __launch_bounds__(256) void pack_mask_kernel(const int* __restrict__ m,
                                                        unsigned long long* __restrict__ o) {
  int i = blockIdx.x * 256 + threadIdx.x;
  unsigned long long b = __ballot(m[i] != 0);
  if ((threadIdx.x & 63) == 0) {
    int row = i >> 11;          // [B*S) row index
    int kt = (i >> 7) & 15;     // 128-kcol tile
    int h = (i >> 6) & 1;       // ull half within tile
    o[(kt * 8192 + row) * 2 + h] = b;
  }
}

// ---------------- fused projections: C = A * W^T for z in {Q,K,V} ----------------
// z=0: Qf bf16 scaled by log2(e)/8 ; z=1: Kf bf16 ; z=2: Vt bf16 permuted [B,H,Dh,S]
__global__ __launch_bounds__(256) void proj_kernel(const unsigned short* __restrict__ A0,
                                                   const unsigned short* __restrict__ A1,
                                                   const unsigned short* __restrict__ A2,
                                                   const unsigned short* __restrict__ W0,
                                                   const unsigned short* __restrict__ W1,
                                                   const unsigned short* __restrict__ W2,
                                                   unsigned short* __restrict__ C0,
                                                   unsigned short* __restrict__ C1,
                                                   unsigned short* __restrict__ C2) {
  __shared__ unsigned short Alds[128 * 32];
  __shared__ unsigned short Blds[128 * 32];
  const int z = blockIdx.z;
  const unsigned short* A = (z == 0) ? A0 : (z == 1) ? A1 : A2;
  const unsigned short* B = (z == 0) ? W0 : (z == 1) ? W1 : W2;
  const int tid = threadIdx.x;
  const int w = tid >> 6, l = tid & 63, q4 = l >> 4, c16 = l & 15;
  const int wm = w & 1, wn = w >> 1;
  const int mBase = blockIdx.y * 128, nBase = blockIdx.x * 128;

  f32x4 acc[4][4];
#pragma unroll
  for (int a0 = 0; a0 < 4; ++a0)
#pragma unroll
    for (int a1 = 0; a1 < 4; ++a1) acc[a0][a1] = (f32x4){0.f, 0.f, 0.f, 0.f};

  const int r0 = tid >> 2, cc0 = tid & 3;

  for (int kt = 0; kt < 32; ++kt) {
    __syncthreads();
    const unsigned short* ga0 = A + (mBase + r0) * 1024 + kt * 32 + cc0 * 8;
    const unsigned short* ga1 = A + (mBase + 64 + r0) * 1024 + kt * 32 + cc0 * 8;
    const unsigned short* gb0 = B + (nBase + r0) * 1024 + kt * 32 + cc0 * 8;
    const unsigned short* gb1 = B + (nBase + 64 + r0) * 1024 + kt * 32 + cc0 * 8;
    __builtin_amdgcn_global_load_lds((const __attribute__((address_space(1))) void*)ga0,
                                     (__attribute__((address_space(3))) void*)(&Alds[tid * 8]),
                                     16, 0, 0);
    __builtin_amdgcn_global_load_lds((const __attribute__((address_space(1))) void*)ga1,
                                     (__attribute__((address_space(3))) void*)(&Alds[(tid + 256) * 8]),
                                     16, 0, 0);
    __builtin_amdgcn_global_load_lds((const __attribute__((address_space(1))) void*)gb0,
                                     (__attribute__((address_space(3))) void*)(&Blds[tid * 8]),
                                     16, 0, 0);
    __builtin_amdgcn_global_load_lds((const __attribute__((address_space(1))) void*)gb1,
                                     (__attribute__((address_space(3))) void*)(&Blds[(tid + 256) * 8]),
                                     16, 0, 0);
    __syncthreads();

    bf16x8 af[4], bfr[4];
#pragma unroll
    for (int mi = 0; mi < 4; ++mi)
      af[mi] = *(const bf16x8*)&Alds[(wm * 64 + mi * 16 + c16) * 32 + q4 * 8];
#pragma unroll
    for (int ni = 0; ni < 4; ++ni)
      bfr[ni] = *(const bf16x8*)&Blds[(wn * 64 + ni * 16 + c16) * 32 + q4 * 8];
#pragma unroll
    for (int mi = 0; mi < 4; ++mi)
#pragma unroll
      for (int ni = 0; ni < 4; ++ni) acc[mi][ni] = MFMA32(af[mi], bfr[ni], acc[mi][ni]);
  }

  const float scale = (z == 0) ? 0.18033688f : 1.0f;  // log2(e)/8 folded into Q
#pragma unroll
  for (int mi = 0; mi < 4; ++mi) {
#pragma unroll
    for (int ni = 0; ni < 4; ++ni) {
#pragma unroll
      for (int rg = 0; rg < 4; ++rg) {
        int row = mBase + wm * 64 + mi * 16 + q4 * 4 + rg;
        int col = nBase + wn * 64 + ni * 16 + c16;
        float v = acc[mi][ni][rg];
        if (z < 2) {
          unsigned short* C = (z == 0) ? C0 : C1;
          C[row * 1024 + col] = fbf(v * scale);
        } else {
          int bb = row >> 11, rr = row & 2047;
          int hh = rr >> 7;
          int ss = ((rr & 127) << 4) | (col >> 6);
          int dh = col & 63;
          C2[((bb * 16 + hh) * 64 + dh) * 2048 + ss] = fbf(v);
        }
      }
    }
  }
}

// ---------------- final GEMM: out = Cws * fc_w^T + bias (fp32 out) ----------------
__global__ __launch_bounds__(256) void gemm_out(const unsigned short* __restrict__ A,
                                                const unsigned short* __restrict__ B,
                                                float* __restrict__ C,
                                                const float* __restrict__ bias) {
  __shared__ unsigned short Alds[128 * 32];
  __shared__ unsigned short Blds[128 * 32];
  const int tid = threadIdx.x;
  const int w = tid >> 6, l = tid & 63, q4 = l >> 4, c16 = l & 15;
  const int wm = w & 1, wn = w >> 1;
  const int mBase = blockIdx.y * 128, nBase = blockIdx.x * 128;

  f32x4 acc[4][4];
#pragma unroll
  for (int a0 = 0; a0 < 4; ++a0)
#pragma unroll
    for (int a1 = 0; a1 < 4; ++a1) acc[a0][a1] = (f32x4){0.f, 0.f, 0.f, 0.f};

  const int r0 = tid >> 2, cc0 = tid & 3;

  for (int kt = 0; kt < 32; ++kt) {
    __syncthreads();
    const unsigned short* ga0 = A + (mBase + r0) * 1024 + kt * 32 + cc0 * 8;
    const unsigned short* ga1 = A + (mBase + 64 + r0) * 1024 + kt * 32 + cc0 * 8;
    const unsigned short* gb0 = B + (nBase + r0) * 1024 + kt * 32 + cc0 * 8;
    const unsigned short* gb1 = B + (nBase + 64 + r0) * 1024 + kt * 32 + cc0 * 8;
    __builtin_amdgcn_global_load_lds((const __attribute__((address_space(1))) void*)ga0,
                                     (__attribute__((address_space(3))) void*)(&Alds[tid * 8]),
                                     16, 0, 0);
    __builtin_amdgcn_global_load_lds((const __attribute__((address_space(1))) void*)ga1,
                                     (__attribute__((address_space(3))) void*)(&Alds[(tid + 256) * 8]),
                                     16, 0, 0);
    __builtin_amdgcn_global_load_lds((const __attribute__((address_space(1))) void*)gb0,
                                     (__attribute__((address_space(3))) void*)(&Blds[tid * 8]),
                                     16, 0, 0);
    __builtin_amdgcn_global_load_lds((const __attribute__((address_space(1))) void*)gb1,
                                     (__attribute__((address_space(3))) void*)(&Blds[(tid + 256) * 8]),
                                     16, 0, 0);
    __syncthreads();

    bf16x8 af[4], bfr[4];
#pragma unroll
    for (int mi = 0; mi < 4; ++mi)
      af[mi] = *(const bf16x8*)&Alds[(wm * 64 + mi * 16 + c16) * 32 + q4 * 8];
#pragma unroll
    for (int ni = 0; ni < 4; ++ni)
      bfr[ni] = *(const bf16x8*)&Blds[(wn * 64 + ni * 16 + c16) * 32 + q4 * 8];
#pragma unroll
    for (int mi = 0; mi < 4; ++mi)
#pragma unroll
      for (int ni = 0; ni < 4; ++ni) acc[mi][ni] = MFMA32(af[mi], bfr[ni], acc[mi][ni]);
  }

#pragma unroll
  for (int mi = 0; mi < 4; ++mi) {
#pragma unroll
    for (int ni = 0; ni < 4; ++ni) {
#pragma unroll
      for (int rg = 0; rg < 4; ++rg) {
        int row = mBase + wm * 64 + mi * 16 + q4 * 4 + rg;
        int col = nBase + wn * 64 + ni * 16 + c16;
        C[row * 1024 + col] = acc[mi][ni][rg] + bias[col];
      }
    }
  }
}

// ---------------- flash attention per (b, h, 128-row q tile) ----------------
// S^T = K·Q^T (P stays in registers); O^T = Vt·P^T with K=32 MFMA via k-permutation:
// lane q4 natively holds kcols {32m+4q4+j, 32m+16+4q4+j}; Vt A-frag loads the
// sigma-matched pair of b64s. Row sums via constant ones A-frag (permutation-invariant).
__global__ __launch_bounds__(256, 4) void flash_kernel(const unsigned short* __restrict__ Q,
                                                       const unsigned short* __restrict__ K,
                                                       const unsigned short* __restrict__ Vt,
                                                       const uint4* __restrict__ mb,
                                                       unsigned short* __restrict__ Cws,
                                                       float* __restrict__ res2) {
  __shared__ unsigned short Klds[128 * 64];   // [kcol][granule ^ (kcol&7)]
  __shared__ unsigned short Vtlds[64 * 128];  // [dh][granule ^ (dh&15)]
  const int tid = threadIdx.x;
  const int w = tid >> 6, l = tid & 63, q4 = l >> 4, c16 = l & 15;
  const int q44 = q4 * 4;
  const int qt = blockIdx.x, h = blockIdx.y, b = blockIdx.z;
  const unsigned short* Qh = Q + (b * 2048 + h * 128) * 1024;
  const unsigned short* Kh = K + (b * 2048 + h * 128) * 1024;
  const unsigned short* Vth = Vt + (b * 16 + h) * 64 * 2048;

  // Q B-frags in registers for all 16 K-tiles
  bf16x8 qf[2][2];
#pragma unroll
  for (int i = 0; i < 2; ++i)
#pragma unroll
    for (int kc = 0; kc < 2; ++kc)
      qf[i][kc] = *(const bf16x8*)(Qh + (qt * 128 + w * 32 + i * 16 + c16) * 64 + kc * 32 + q4 * 8);

  const int rowi = b * 2048 + qt * 128 + w * 32 + c16;  // mask row, i=0 (i=1: +16)

  // staging lane offsets (global side carries the swizzle; LDS side is lane-linear)
  const int kOff = (tid >> 3) * 64 + (((tid & 7) ^ ((tid >> 3) & 7)) * 8);
  const int vOff = (tid >> 4) * 2048 + (((tid & 15) ^ (tid >> 4)) * 8);

  // QK read lane base: row=16n+c16, phys granule q4^(c16&7) (content = global granule q4)
  const int kb0 = c16 * 64 + ((q4 ^ (c16 & 7)) * 8);
  const int kb1 = kb0 ^ 32;
  // PV read: row=16t+c16, global granule gLo=4m+(q4>>1) (hi: +2), phys = g ^ c16, half q4&1
  const int vb = c16 * 128 + (q4 & 1) * 4;
  const int q41 = q4 >> 1;

  const bf16x8 ones8 = {(short)0x3F80, (short)0x3F80, (short)0x3F80, (short)0x3F80,
                        (short)0x3F80, (short)0x3F80, (short)0x3F80, (short)0x3F80};

  f32x4 oacc[2][4], soacc[2];
#pragma unroll
  for (int i = 0; i < 2; ++i) {
    soacc[i] = (f32x4){0.f, 0.f, 0.f, 0.f};
#pragma unroll
    for (int t = 0; t < 4; ++t) oacc[i][t] = (f32x4){0.f, 0.f, 0.f, 0.f};
  }

  for (int kt = 0; kt < 16; ++kt) {
    const unsigned short* gk = Kh + kt * 8192 + kOff;
    const unsigned short* gv = Vth + kt * 128 + vOff;
#pragma unroll
    for (int j = 0; j < 4; ++j) {
      __builtin_amdgcn_global_load_lds((const __attribute__((address_space(1))) void*)(gk + j * 2048),
                                       (__attribute__((address_space(3))) void*)(&Klds[(j * 256 + tid) * 8]),
                                       16, 0, 0);
      __builtin_amdgcn_global_load_lds((const __attribute__((address_space(1))) void*)(gv + j * 32768),
                                       (__attribute__((address_space(3))) void*)(&Vtlds[(j * 256 + tid) * 8]),
                                       16, 0, 0);
    }
    // coalesced kt-major mask load (overlaps the DMA)
    uint4 m0 = mb[kt * 8192 + rowi];
    uint4 m1 = mb[kt * 8192 + rowi + 16];
    unsigned pre0[4] = {m0.x >> q44, m0.y >> q44, m0.z >> q44, m0.w >> q44};
    unsigned pre1[4] = {m1.x >> q44, m1.y >> q44, m1.z >> q44, m1.w >> q44};
    __syncthreads();

#pragma unroll
    for (int m = 0; m < 4; ++m) {  // pair of 16-kcol chunks: n = 2m, 2m+1
      bf16x8 kfE0 = *(const bf16x8*)(Klds + kb0 + (2 * m) * 1024);
      bf16x8 kfE1 = *(const bf16x8*)(Klds + kb1 + (2 * m) * 1024);
      bf16x8 kfO0 = *(const bf16x8*)(Klds + kb0 + (2 * m + 1) * 1024);
      bf16x8 kfO1 = *(const bf16x8*)(Klds + kb1 + (2 * m + 1) * 1024);
      f32x4 sE0 = {0.f, 0.f, 0.f, 0.f}, sE1 = {0.f, 0.f, 0.f, 0.f};
      f32x4 sO0 = {0.f, 0.f, 0.f, 0.f}, sO1 = {0.f, 0.f, 0.f, 0.f};
      sE0 = MFMA32(kfE0, qf[0][0], sE0); sE0 = MFMA32(kfE1, qf[0][1], sE0);
      sE1 = MFMA32(kfE0, qf[1][0], sE1); sE1 = MFMA32(kfE1, qf[1][1], sE1);
      sO0 = MFMA32(kfO0, qf[0][0], sO0); sO0 = MFMA32(kfO1, qf[0][1], sO0);
      sO1 = MFMA32(kfO0, qf[1][0], sO1); sO1 = MFMA32(kfO1, qf[1][1], sO1);

      int shE = 0, shO = 16;  // kcol bit position within 32-bit mask word m
      bf16x8 pf0 = cat2(epp(sE0, pre0[m], shE), epp(sO0, pre0[m], shO));
      bf16x8 pf1 = cat2(epp(sE1, pre1[m], shE), epp(sO1, pre1[m], shO));

      int pLo = (4 * m + q41) ^ c16;
      int aLo = vb + pLo * 8;
#pragma unroll
      for (int t = 0; t < 4; ++t) {
        bf16x4 vlo = *(const bf16x4*)(Vtlds + aLo + t * 2048);
        bf16x4 vhi = *(const bf16x4*)(Vtlds + (aLo ^ 16) + t * 2048);
        bf16x8 vf8 = cat2(vlo, vhi);
        oacc[0][t] = MFMA32(vf8, pf0, oacc[0][t]);
        oacc[1][t] = MFMA32(vf8, pf1, oacc[1][t]);
      }
      soacc[0] = MFMA32(ones8, pf0, soacc[0]);
      soacc[1] = MFMA32(ones8, pf1, soacc[1]);
    }
    __syncthreads();
  }

  // epilogue: lane (c16,q4) holds O[q=base+i*16+c16][dh=16t+q44+rg]; soacc = rowsum(q)
#pragma unroll
  for (int i = 0; i < 2; ++i) {
    float sum = soacc[i][0];
    float rcp = (sum > 0.f) ? (1.0f / sum) : 0.f;  // sum==0 -> 0 reproduces NaN->0
    int q = qt * 128 + w * 32 + i * 16 + c16;
    float* rp = res2 + (((h * 4 + b) * 2048 + q) * 64 + q44);
    unsigned short* cp = Cws + ((b * 2048 + q) * 1024 + h * 64 + q44);
#pragma unroll
    for (int t = 0; t < 4; ++t) {
      float o0 = oacc[i][t][0] * rcp, o1 = oacc[i][t][1] * rcp;
      float o2 = oacc[i][t][2] * rcp, o3 = oacc[i][t][3] * rcp;
      float4 fo = {o0, o1, o2, o3};
      *(float4*)(rp + t * 16) = fo;
      ushort4 cv = {fbf(o0), fbf(o1), fbf(o2), fbf(o3)};
      *(ushort4*)(cp + t * 16) = cv;
    }
  }
}

extern "C" void kernel_launch(void* const* d_in, const int* in_sizes, int n_in,
                              void* d_out, int out_size, void* d_ws, size_t ws_size,
                              hipStream_t stream) {
  const float* query = (const float*)d_in[0];
  const float* key_t = (const float*)d_in[1];
  const float* value = (const float*)d_in[2];
  const int* mask = (const int*)d_in[3];
  const float* Wq = (const float*)d_in[4];
  const float* Wk = (const float*)d_in[5];
  const float* Wv = (const float*)d_in[6];
  const float* fcw = (const float*)d_in[7];
  const float* fcb = (const float*)d_in[8];
  float* out = (float*)d_out;

  char* ws = (char*)d_ws;
  unsigned short* qbf = (unsigned short*)(ws);                      // 16MB (later: Cws)
  unsigned short* kbf = (unsigned short*)(ws + (16u << 20));        // 16MB (later: mask bits)
  unsigned short* vbf = (unsigned short*)(ws + (32u << 20));        // 16MB
  unsigned short* wqb = (unsigned short*)(ws + (48u << 20));        // 2MB
  unsigned short* wkb = (unsigned short*)(ws + (50u << 20));
  unsigned short* wvb = (unsigned short*)(ws + (52u << 20));
  unsigned short* fwb = (unsigned short*)(ws + (54u << 20));
  unsigned short* Qf = (unsigned short*)(ws + (56u << 20));         // 16MB
  unsigned short* Kf = (unsigned short*)(ws + (72u << 20));         // 16MB
  unsigned short* Vt = (unsigned short*)(ws + (88u << 20));         // 16MB; total 104MB
  unsigned short* Cws = qbf;                                        // alias (qbf dead after proj)
  unsigned long long* mbits = (unsigned long long*)kbf;             // alias (kbf dead after proj)

  f2b3_kernel<<<dim3(8192, 3), 256, 0, stream>>>(query, key_t, value, qbf, kbf, vbf);
  f2b4_kernel<<<dim3(1024, 4), 256, 0, stream>>>(Wq, Wk, Wv, fcw, wqb, wkb, wvb, fwb);

  proj_kernel<<<dim3(8, 64, 3), 256, 0, stream>>>(qbf, kbf, vbf, wqb, wkb, wvb, Qf, Kf, Vt);

  pack_mask_kernel<<<65536, 256, 0, stream>>>(mask, mbits);

  flash_kernel<<<dim3(16, 16, 4), 256, 0, stream>>>(Qf, Kf, Vt, (const uint4*)mbits, Cws,
                                                    out + 8388608);

  gemm_out<<<dim3(8, 64), 256, 0, stream>>>(Cws, fwb, out, fcb);
}